// Round 3
// baseline (314.037 us; speedup 1.0000x reference)
//
#include <hip/hip_runtime.h>

// y_pred: [2, 2, 128, 256, 256] f32   y_true: [2, 128, 256, 256] i32
// C=2 -> argmax over positive classes == 1 always; only channel 1 of y_pred
// is read. Whole op reduces to 3 counters: ct=#(yt==1), cp=#(p>0.5),
// cb=#(both); cm/tps/fps/fns/tns are closed forms of {ct,cp,cb,N}.
static constexpr long long PER_BATCH = 128LL * 256 * 256;   // 8,388,608 elems
static constexpr long long N_TOTAL   = 2 * PER_BATCH;       // 16,777,216

static constexpr int TPB    = 256;
static constexpr int BLOCKS = 2048;                 // 8 blocks/CU
static constexpr int BPB    = BLOCKS / 2;           // 1024 blocks per batch
static constexpr int VEC_PER_BLOCK = (int)(PER_BATCH / 4 / BPB);  // 2048 vec4 = 32 KB/stream
static constexpr int ITERS  = VEC_PER_BLOCK / TPB;  // 8

// ws layout: ws[0..2] = {ct,cp,cb} counters, ws[3] = ticket. Zeroed by a
// 16-byte hipMemsetAsync each call (ws is re-poisoned to 0xAA by harness).
__global__ __launch_bounds__(TPB) void _cm_count_kernel(
        const float* __restrict__ y_pred,
        const int*   __restrict__ y_true,
        unsigned int* __restrict__ ws,
        int* __restrict__ out) {
    const int b     = blockIdx.x;
    const int batch = b >> 10;               // BPB == 1024
    const int r     = b & (BPB - 1);
    const int tx    = threadIdx.x;

    // Block-contiguous slabs: 32-bit offsets, sequential DRAM access per block.
    const int4*   __restrict__ tv =
        reinterpret_cast<const int4*>(y_true + (long long)batch * PER_BATCH);
    const float4* __restrict__ pv =
        reinterpret_cast<const float4*>(y_pred + (long long)(2 * batch + 1) * PER_BATCH);
    const int base = r * VEC_PER_BLOCK + tx;

    // Issue all 16 loads back-to-back (compile-time offsets) for max MLP.
    int4   t[ITERS];
    float4 p[ITERS];
    #pragma unroll
    for (int i = 0; i < ITERS; ++i) t[i] = tv[base + i * TPB];
    #pragma unroll
    for (int i = 0; i < ITERS; ++i) p[i] = pv[base + i * TPB];

    unsigned int ct = 0, cp = 0, cb = 0;
    #pragma unroll
    for (int i = 0; i < ITERS; ++i) {
        unsigned int t0 = (t[i].x == 1), t1 = (t[i].y == 1), t2 = (t[i].z == 1), t3 = (t[i].w == 1);
        unsigned int q0 = (p[i].x > 0.5f), q1 = (p[i].y > 0.5f), q2 = (p[i].z > 0.5f), q3 = (p[i].w > 0.5f);
        ct += t0 + t1 + t2 + t3;
        cp += q0 + q1 + q2 + q3;
        cb += (t0 & q0) + (t1 & q1) + (t2 & q2) + (t3 & q3);
    }

    // wave64 shuffle reduction
    #pragma unroll
    for (int off = 32; off > 0; off >>= 1) {
        ct += __shfl_down(ct, off);
        cp += __shfl_down(cp, off);
        cb += __shfl_down(cb, off);
    }

    __shared__ unsigned int s[3][4];         // 4 waves/block
    __shared__ int lastFlag;
    const int wave = tx >> 6;
    if ((tx & 63) == 0) { s[0][wave] = ct; s[1][wave] = cp; s[2][wave] = cb; }
    __syncthreads();

    if (tx == 0) {
        unsigned int bct = s[0][0] + s[0][1] + s[0][2] + s[0][3];
        unsigned int bcp = s[1][0] + s[1][1] + s[1][2] + s[1][3];
        unsigned int bcb = s[2][0] + s[2][1] + s[2][2] + s[2][3];
        atomicAdd(&ws[0], bct);              // device-scope by default (G12)
        atomicAdd(&ws[1], bcp);
        atomicAdd(&ws[2], bcb);
        __threadfence();                     // counters visible before ticket
        lastFlag = (atomicAdd(&ws[3], 1u) == (unsigned)(BLOCKS - 1));
    }
    __syncthreads();

    // Last block to finish folds counters into the 8 outputs (G16: atomics
    // bypass L1, ticket acquire + fence orders the counter reads).
    if (tx == 0 && lastFlag) {
        __threadfence();
        int fct = (int)atomicAdd(&ws[0], 0u);   // atomic read -> L2, never stale L1
        int fcp = (int)atomicAdd(&ws[1], 0u);
        int fcb = (int)atomicAdd(&ws[2], 0u);
        int cm11 = fcb;
        int cm10 = fct - fcb;
        int cm01 = fcp - fcb;
        int cm00 = (int)N_TOTAL - fct - fcp + fcb;
        out[0] = cm00; out[1] = cm01;
        out[2] = cm10; out[3] = cm11;
        out[4] = cm11;   // tps[1]
        out[5] = cm01;   // fps[1]
        out[6] = cm10;   // fns[1]
        out[7] = cm00;   // tns[1]
    }
}

extern "C" void kernel_launch(void* const* d_in, const int* in_sizes, int n_in,
                              void* d_out, int out_size, void* d_ws, size_t ws_size,
                              hipStream_t stream) {
    const float* y_pred = (const float*)d_in[0];
    const int*   y_true = (const int*)d_in[1];
    unsigned int* ws = (unsigned int*)d_ws;
    int* out = (int*)d_out;

    hipMemsetAsync(ws, 0, 4 * sizeof(unsigned int), stream);  // counters + ticket
    _cm_count_kernel<<<BLOCKS, TPB, 0, stream>>>(y_pred, y_true, ws, out);
}

// Round 4
// 217.424 us; speedup vs baseline: 1.4444x; 1.4444x over previous
//
#include <hip/hip_runtime.h>

// y_pred: [2, 2, 128, 256, 256] f32   y_true: [2, 128, 256, 256] i32
// C=2 -> only channel 1 of y_pred is read; op reduces to 3 counters
// ct=#(yt==1), cp=#(p>0.5), cb=#(both).
//
// R4 structure: TWO single-stream passes (R3's atomic hotspot regressed 2x;
// R2's dual-stream-per-thread kernel stuck at ~3 TB/s effective).
//   A: read y_pred ch1 (67 MB) -> nibble mask (4 MB in ws) + cp partials
//   B: read y_true (67 MB) + mask (L2/L3-hot) -> ct, cb partials
//   C: finalize 3x2048 partials -> 8 outputs
static constexpr long long PER_BATCH = 128LL * 256 * 256;   // 8,388,608 elems
static constexpr long long N_TOTAL   = 2 * PER_BATCH;       // 16,777,216
static constexpr long long NVB       = PER_BATCH / 4;       // 2,097,152 vec4/batch

static constexpr int       BLOCKS = 2048;
static constexpr int       TPB    = 256;
static constexpr long long T      = (long long)BLOCKS * TPB; // 524,288 threads
// 8 vec4-iters/thread; 4*T == NVB so iters 0..3 are batch0, 4..7 batch1,
// both indexed tid + i*T off their own channel-1 base.

// ws layout: [0, 4MB) mask64[524288]; then cp[2048], ct[2048], cb[2048].
static constexpr size_t MASK_U64 = (size_t)T;               // one u64 per A-thread

__device__ __forceinline__ void block_reduce_store(unsigned int v,
                                                   unsigned int* __restrict__ dst) {
    #pragma unroll
    for (int off = 32; off > 0; off >>= 1) v += __shfl_down(v, off);
    __shared__ unsigned int s[4];
    const int wave = threadIdx.x >> 6;
    if ((threadIdx.x & 63) == 0) s[wave] = v;
    __syncthreads();
    if (threadIdx.x == 0) dst[blockIdx.x] = s[0] + s[1] + s[2] + s[3];
}

__global__ __launch_bounds__(TPB) void _cm_pred_kernel(
        const float* __restrict__ y_pred,
        unsigned long long* __restrict__ mask64,
        unsigned int* __restrict__ cp_part) {
    const long long tid = (long long)blockIdx.x * TPB + threadIdx.x;
    const float4* __restrict__ p0 = reinterpret_cast<const float4*>(y_pred + PER_BATCH);
    const float4* __restrict__ p1 = reinterpret_cast<const float4*>(y_pred + 3 * PER_BATCH);

    float4 p[8];
    #pragma unroll
    for (int i = 0; i < 4; ++i) p[i] = p0[tid + i * T];
    #pragma unroll
    for (int i = 0; i < 4; ++i) p[i + 4] = p1[tid + i * T];

    unsigned long long m = 0;
    #pragma unroll
    for (int i = 0; i < 8; ++i) {
        unsigned int b = (unsigned int)(p[i].x > 0.5f)
                       | ((unsigned int)(p[i].y > 0.5f) << 1)
                       | ((unsigned int)(p[i].z > 0.5f) << 2)
                       | ((unsigned int)(p[i].w > 0.5f) << 3);
        m |= (unsigned long long)b << (8 * i);
    }
    mask64[tid] = m;
    block_reduce_store((unsigned int)__popcll(m), cp_part);
}

__global__ __launch_bounds__(TPB) void _cm_true_kernel(
        const int* __restrict__ y_true,
        const unsigned long long* __restrict__ mask64,
        unsigned int* __restrict__ ct_part,
        unsigned int* __restrict__ cb_part) {
    const long long tid = (long long)blockIdx.x * TPB + threadIdx.x;
    const int4* __restrict__ tv = reinterpret_cast<const int4*>(y_true);

    int4 t[8];
    #pragma unroll
    for (int i = 0; i < 8; ++i) t[i] = tv[tid + i * T];
    const unsigned long long m = mask64[tid];

    unsigned int ct = 0, cb = 0;
    #pragma unroll
    for (int i = 0; i < 8; ++i) {
        unsigned int t0 = (t[i].x == 1), t1 = (t[i].y == 1),
                     t2 = (t[i].z == 1), t3 = (t[i].w == 1);
        unsigned int bi = (unsigned int)(m >> (8 * i)) & 0xFu;
        ct += t0 + t1 + t2 + t3;
        cb += (t0 & (bi & 1u)) + (t1 & ((bi >> 1) & 1u))
            + (t2 & ((bi >> 2) & 1u)) + (t3 & ((bi >> 3) & 1u));
    }

    #pragma unroll
    for (int off = 32; off > 0; off >>= 1) {
        ct += __shfl_down(ct, off);
        cb += __shfl_down(cb, off);
    }
    __shared__ unsigned int s[2][4];
    const int wave = threadIdx.x >> 6;
    if ((threadIdx.x & 63) == 0) { s[0][wave] = ct; s[1][wave] = cb; }
    __syncthreads();
    if (threadIdx.x == 0) {
        ct_part[blockIdx.x] = s[0][0] + s[0][1] + s[0][2] + s[0][3];
        cb_part[blockIdx.x] = s[1][0] + s[1][1] + s[1][2] + s[1][3];
    }
}

__global__ __launch_bounds__(TPB) void _cm_finalize_kernel(
        const unsigned int* __restrict__ cp_part,
        const unsigned int* __restrict__ ct_part,
        const unsigned int* __restrict__ cb_part,
        int* __restrict__ out) {
    unsigned int cp = 0, ct = 0, cb = 0;
    #pragma unroll
    for (int i = 0; i < BLOCKS / TPB; ++i) {
        cp += cp_part[threadIdx.x + i * TPB];
        ct += ct_part[threadIdx.x + i * TPB];
        cb += cb_part[threadIdx.x + i * TPB];
    }
    #pragma unroll
    for (int off = 32; off > 0; off >>= 1) {
        cp += __shfl_down(cp, off);
        ct += __shfl_down(ct, off);
        cb += __shfl_down(cb, off);
    }
    __shared__ unsigned int s[3][4];
    const int wave = threadIdx.x >> 6;
    if ((threadIdx.x & 63) == 0) { s[0][wave] = cp; s[1][wave] = ct; s[2][wave] = cb; }
    __syncthreads();
    if (threadIdx.x == 0) {
        int fcp = (int)(s[0][0] + s[0][1] + s[0][2] + s[0][3]);
        int fct = (int)(s[1][0] + s[1][1] + s[1][2] + s[1][3]);
        int fcb = (int)(s[2][0] + s[2][1] + s[2][2] + s[2][3]);
        int cm11 = fcb;
        int cm10 = fct - fcb;
        int cm01 = fcp - fcb;
        int cm00 = (int)N_TOTAL - fct - fcp + fcb;
        out[0] = cm00; out[1] = cm01;
        out[2] = cm10; out[3] = cm11;
        out[4] = cm11;   // tps[1]
        out[5] = cm01;   // fps[1]
        out[6] = cm10;   // fns[1]
        out[7] = cm00;   // tns[1]
    }
}

extern "C" void kernel_launch(void* const* d_in, const int* in_sizes, int n_in,
                              void* d_out, int out_size, void* d_ws, size_t ws_size,
                              hipStream_t stream) {
    const float* y_pred = (const float*)d_in[0];
    const int*   y_true = (const int*)d_in[1];
    unsigned long long* mask64 = (unsigned long long*)d_ws;
    unsigned int* cp_part = (unsigned int*)((char*)d_ws + MASK_U64 * 8);
    unsigned int* ct_part = cp_part + BLOCKS;
    unsigned int* cb_part = ct_part + BLOCKS;
    int* out = (int*)d_out;

    _cm_pred_kernel<<<BLOCKS, TPB, 0, stream>>>(y_pred, mask64, cp_part);
    _cm_true_kernel<<<BLOCKS, TPB, 0, stream>>>(y_true, mask64, ct_part, cb_part);
    _cm_finalize_kernel<<<1, TPB, 0, stream>>>(cp_part, ct_part, cb_part, out);
}

// Round 5
// 203.382 us; speedup vs baseline: 1.5441x; 1.0690x over previous
//
#include <hip/hip_runtime.h>

// y_pred: [2, 2, 128, 256, 256] f32   y_true: [2, 128, 256, 256] i32
// C=2 -> only channel 1 of y_pred is read; op reduces to 3 counters
// ct=#(yt==1), cp=#(p>0.5), cb=#(both). Outputs are closed forms.
//
// R5: single fused count kernel (R2 structure, best so far at ~2.9 TB/s read),
// + nontemporal loads + 4096-block turnover. Testing whether the ~3 TB/s
// one-way read ceiling (copy/LN/RMSNorm/R2/R4 all cluster at 2.5-3.2) can
// be exceeded; if not, this is the read-path roofline.
static constexpr long long PER_BATCH = 128LL * 256 * 256;   // 8,388,608 elems
static constexpr long long N_TOTAL   = 2 * PER_BATCH;       // 16,777,216

static constexpr int TPB    = 256;
static constexpr int BLOCKS = 4096;
static constexpr int T2     = BLOCKS * TPB;                 // 1,048,576 threads
// y_true: 4,194,304 vec4 = 4*T2 -> 4 t-loads/thread at stride T2.
// y_pred ch1: two contiguous chunks of 2*T2 vec4 each -> 2+2 p-loads/thread.
// Element alignment: t[i] and p[i] both cover flat vec-index tid + i*T2.

typedef float v4f __attribute__((ext_vector_type(4)));
typedef int   v4i __attribute__((ext_vector_type(4)));

__global__ __launch_bounds__(TPB) void _cm_count_kernel(
        const float* __restrict__ y_pred,
        const int*   __restrict__ y_true,
        unsigned int* __restrict__ partials) {   // [3][BLOCKS]
    const int tid = blockIdx.x * TPB + threadIdx.x;

    const v4i* __restrict__ tv = reinterpret_cast<const v4i*>(y_true);
    const v4f* __restrict__ p0 = reinterpret_cast<const v4f*>(y_pred + PER_BATCH);      // b0 ch1
    const v4f* __restrict__ p1 = reinterpret_cast<const v4f*>(y_pred + 3 * PER_BATCH);  // b1 ch1

    // Issue all 8 loads back-to-back, nontemporal (streaming, no cache alloc).
    v4i t[4];
    v4f p[4];
    #pragma unroll
    for (int i = 0; i < 4; ++i) t[i] = __builtin_nontemporal_load(&tv[tid + i * T2]);
    #pragma unroll
    for (int i = 0; i < 2; ++i) p[i] = __builtin_nontemporal_load(&p0[tid + i * T2]);
    #pragma unroll
    for (int i = 0; i < 2; ++i) p[2 + i] = __builtin_nontemporal_load(&p1[tid + i * T2]);

    unsigned int ct = 0, cp = 0, cb = 0;
    #pragma unroll
    for (int i = 0; i < 4; ++i) {
        unsigned int t0 = (t[i].x == 1), t1 = (t[i].y == 1),
                     t2 = (t[i].z == 1), t3 = (t[i].w == 1);
        unsigned int q0 = (p[i].x > 0.5f), q1 = (p[i].y > 0.5f),
                     q2 = (p[i].z > 0.5f), q3 = (p[i].w > 0.5f);
        ct += t0 + t1 + t2 + t3;
        cp += q0 + q1 + q2 + q3;
        cb += (t0 & q0) + (t1 & q1) + (t2 & q2) + (t3 & q3);
    }

    // wave64 shuffle reduction, then per-block partial store (no atomics).
    #pragma unroll
    for (int off = 32; off > 0; off >>= 1) {
        ct += __shfl_down(ct, off);
        cp += __shfl_down(cp, off);
        cb += __shfl_down(cb, off);
    }
    __shared__ unsigned int s[3][4];
    const int wave = threadIdx.x >> 6;
    if ((threadIdx.x & 63) == 0) { s[0][wave] = ct; s[1][wave] = cp; s[2][wave] = cb; }
    __syncthreads();
    if (threadIdx.x == 0) {
        partials[             blockIdx.x] = s[0][0] + s[0][1] + s[0][2] + s[0][3];
        partials[    BLOCKS + blockIdx.x] = s[1][0] + s[1][1] + s[1][2] + s[1][3];
        partials[2 * BLOCKS + blockIdx.x] = s[2][0] + s[2][1] + s[2][2] + s[2][3];
    }
}

__global__ __launch_bounds__(TPB) void _cm_finalize_kernel(
        const unsigned int* __restrict__ partials,
        int* __restrict__ out) {
    unsigned int ct = 0, cp = 0, cb = 0;
    #pragma unroll
    for (int i = 0; i < BLOCKS / TPB; ++i) {
        ct += partials[             threadIdx.x + i * TPB];
        cp += partials[    BLOCKS + threadIdx.x + i * TPB];
        cb += partials[2 * BLOCKS + threadIdx.x + i * TPB];
    }
    #pragma unroll
    for (int off = 32; off > 0; off >>= 1) {
        ct += __shfl_down(ct, off);
        cp += __shfl_down(cp, off);
        cb += __shfl_down(cb, off);
    }
    __shared__ unsigned int s[3][4];
    const int wave = threadIdx.x >> 6;
    if ((threadIdx.x & 63) == 0) { s[0][wave] = ct; s[1][wave] = cp; s[2][wave] = cb; }
    __syncthreads();
    if (threadIdx.x == 0) {
        int fct = (int)(s[0][0] + s[0][1] + s[0][2] + s[0][3]);
        int fcp = (int)(s[1][0] + s[1][1] + s[1][2] + s[1][3]);
        int fcb = (int)(s[2][0] + s[2][1] + s[2][2] + s[2][3]);
        int cm11 = fcb;
        int cm10 = fct - fcb;
        int cm01 = fcp - fcb;
        int cm00 = (int)N_TOTAL - fct - fcp + fcb;
        out[0] = cm00; out[1] = cm01;
        out[2] = cm10; out[3] = cm11;
        out[4] = cm11;   // tps[1]
        out[5] = cm01;   // fps[1]
        out[6] = cm10;   // fns[1]
        out[7] = cm00;   // tns[1]
    }
}

extern "C" void kernel_launch(void* const* d_in, const int* in_sizes, int n_in,
                              void* d_out, int out_size, void* d_ws, size_t ws_size,
                              hipStream_t stream) {
    const float* y_pred = (const float*)d_in[0];
    const int*   y_true = (const int*)d_in[1];
    unsigned int* partials = (unsigned int*)d_ws;   // 3*BLOCKS u32, fully overwritten
    int* out = (int*)d_out;

    _cm_count_kernel<<<BLOCKS, TPB, 0, stream>>>(y_pred, y_true, partials);
    _cm_finalize_kernel<<<1, TPB, 0, stream>>>(partials, out);
}